// Round 18
// baseline (49.915 us; speedup 1.0000x reference)
//
#include <hip/hip_runtime.h>

// CCAMDec: out = x + scale * softmax(max_k(E)-E) @ y,  E = x·yᵀ over HW
// N=8, C=512, K=64, HW=4096. softmax(max-E) == softmax(-E) (shift invariance).
#define N_ 8
#define C_ 512
#define K_ 64
#define HW_ 4096

typedef __attribute__((ext_vector_type(8))) short short8;   // 8 bf16 (4 VGPRs) MFMA A/B frag
typedef __attribute__((ext_vector_type(4))) float floatx4;  // MFMA C/D frag

// 8 f32 -> 8 bf16 via hardware v_cvt_pk_bf16_f32 (RNE, 1 instr / 2 elems)
__device__ __forceinline__ short8 cvt8(const float* __restrict__ p){
  float4 u = *(const float4*)p;
  float4 w = *(const float4*)(p + 4);
  union { unsigned u32[4]; short8 s; } r;
  asm("v_cvt_pk_bf16_f32 %0, %1, %2" : "=v"(r.u32[0]) : "v"(u.x), "v"(u.y));
  asm("v_cvt_pk_bf16_f32 %0, %1, %2" : "=v"(r.u32[1]) : "v"(u.z), "v"(u.w));
  asm("v_cvt_pk_bf16_f32 %0, %1, %2" : "=v"(r.u32[2]) : "v"(w.x), "v"(w.y));
  asm("v_cvt_pk_bf16_f32 %0, %1, %2" : "=v"(r.u32[3]) : "v"(w.z), "v"(w.w));
  return r.s;
}

// async global -> LDS, 16 B/lane (1 KB/wave), zero VGPR cost
__device__ __forceinline__ void gload16(const void* g, void* l){
  __builtin_amdgcn_global_load_lds(
      (const __attribute__((address_space(1))) void*)g,
      (__attribute__((address_space(3))) void*)l, 16, 0, 0);
}

// K0: y (f32, [n][k][s]) -> ybf (bf16 row-major [n][k][s]) and ytr (bf16 [n][s][k])
__global__ __launch_bounds__(256) void k_prep(const float* __restrict__ y,
                                              unsigned short* __restrict__ ybf,
                                              unsigned short* __restrict__ ytr){
  __shared__ unsigned short tile[64][72];
  int n  = blockIdx.x >> 6;                 // 64 s-tiles per batch
  int s0 = (blockIdx.x & 63) << 6;
  int tid = threadIdx.x;
  int k  = tid >> 2;
  int sc = (tid & 3) << 4;
  const float* yp = y + ((size_t)n * K_ + k) * HW_ + s0 + sc;
  union { unsigned short u16[16]; short8 s8[2]; uint4 q[2]; } u;
  u.s8[0] = cvt8(yp);
  u.s8[1] = cvt8(yp + 8);
  unsigned short* rp = ybf + ((size_t)n * K_ + k) * HW_ + s0 + sc;
  *(uint4*)rp       = u.q[0];
  *(uint4*)(rp + 8) = u.q[1];
#pragma unroll
  for (int j = 0; j < 16; ++j) tile[sc + j][k] = u.u16[j];
  __syncthreads();
  int s  = tid >> 2;
  int kc = (tid & 3) << 4;
  unsigned short* tp = ytr + ((size_t)n * HW_ + s0 + s) * K_ + kc;
  *(uint4*)tp       = *(const uint4*)&tile[s][kc];
  *(uint4*)(tp + 8) = *(const uint4*)&tile[s][kc + 8];
}

// K1: half-range energy, R17's barrier-free wave-private engine at
// 2 blocks/CU.  Grid 512 = (n, 16c, s-half=2048).  512 thr (8 waves).
// Wave (h=w>>2? no: h=w>>2 in R17; here h=w>>2 is 0..1) — wave (h=w>>2,
// q=w&3): s-slice [h*32,+32) of each 64-s chunk, k-quad q.  Per chunk:
// 2 A-gloads (16 c-rows x 32 s, x dup 4x -> L2) + 1 B-gload, private 3KB
// double-buffer, granule-XOR pre-swizzle, vmcnt(3), ZERO barriers in loop.
// Epilogue: LDS h-reduce (aliased onto drained staging) -> one float4
// store/thread into partial[half] (plain stores, no sync — R14/R15 lesson).
__global__ __launch_bounds__(512) void k_esm(const float* __restrict__ x,
                                             const unsigned short* __restrict__ ybf,
                                             float* __restrict__ partial){
  __shared__ char smem[49152];      // 8 waves x 6 KB private staging
  const int bid = ((blockIdx.x & 7) << 6) | (blockIdx.x >> 3);  // XCD swizzle (512%8==0)
  const int half = bid & 1, ct = (bid >> 1) & 31, n = bid >> 6;
  const int tid = threadIdx.x;
  const int w = tid >> 6, l = tid & 63;
  const int lo = l & 15, hi = l >> 4;
  const int h = w >> 2, q = w & 3;          // h in {0,1}
  const int c0 = ct << 4;
  const int sb = half << 11;                // 2048 s per block

  // per-lane source addresses (chunk-invariant, granule-XOR pre-swizzled)
  const int ar = l >> 3;
  const int ag = (l & 7) ^ ar;              // true s-granule (4 f32)
  const char* asrc0 = (const char*)(x + ((size_t)n * C_ + c0 + 0 + ar) * HW_
                                    + sb + h * 32 + ag * 4);
  const char* asrc1 = (const char*)(x + ((size_t)n * C_ + c0 + 8 + ar) * HW_
                                    + sb + h * 32 + ag * 4);
  const int br = l >> 2;
  const int bg = (l & 3) ^ (br & 3);
  const char* bsrc = (const char*)(ybf + ((size_t)n * K_ + (q << 4) + br) * HW_
                                   + sb + h * 32 + bg * 8);

  char* wbase = smem + w * 6144;    // wave-private: [2 bufs][A 2K | B 1K]
  floatx4 acc = {0.f, 0.f, 0.f, 0.f};

#define ESTG(BUF, CH)                                                          \
  {                                                                            \
    gload16(asrc0 + (size_t)(CH) * 256, wbase + (BUF) * 3072);                 \
    gload16(asrc1 + (size_t)(CH) * 256, wbase + (BUF) * 3072 + 1024);          \
    gload16(bsrc  + (size_t)(CH) * 128, wbase + (BUF) * 3072 + 2048);          \
  }

#define ECMP(BUF)                                                              \
  {                                                                            \
    const char* Ab = wbase + (BUF) * 3072;                                     \
    float4 f0 = *(const float4*)(Ab + lo * 128 + (((hi << 1)       ^ (lo & 7)) << 4)); \
    float4 f1 = *(const float4*)(Ab + lo * 128 + ((((hi << 1) | 1) ^ (lo & 7)) << 4)); \
    union { unsigned u32[4]; short8 s; } xf;                                   \
    asm("v_cvt_pk_bf16_f32 %0, %1, %2" : "=v"(xf.u32[0]) : "v"(f0.x), "v"(f0.y)); \
    asm("v_cvt_pk_bf16_f32 %0, %1, %2" : "=v"(xf.u32[1]) : "v"(f0.z), "v"(f0.w)); \
    asm("v_cvt_pk_bf16_f32 %0, %1, %2" : "=v"(xf.u32[2]) : "v"(f1.x), "v"(f1.y)); \
    asm("v_cvt_pk_bf16_f32 %0, %1, %2" : "=v"(xf.u32[3]) : "v"(f1.z), "v"(f1.w)); \
    short8 yf = *(const short8*)(Ab + 2048 + lo * 64 + ((hi ^ (lo & 3)) << 4)); \
    /* swapped: A = y-frag (M=k), B = x-frag (N=c) -> D col=lo->c, row->k */   \
    acc = __builtin_amdgcn_mfma_f32_16x16x32_bf16(yf, xf.s, acc, 0, 0, 0);     \
  }

  ESTG(0, 0) ESTG(1, 1)            // 6 loads in flight

  for (int cp = 0; cp < 15; ++cp){
    int ch = cp << 1;
    asm volatile("s_waitcnt vmcnt(3)" ::: "memory");   // chunk ch ready
    ECMP(0)
    ESTG(0, ch + 2)
    asm volatile("s_waitcnt vmcnt(3)" ::: "memory");   // chunk ch+1 ready
    ECMP(1)
    ESTG(1, ch + 3)
  }
  asm volatile("s_waitcnt vmcnt(3)" ::: "memory");     // ch=30
  ECMP(0)
  asm volatile("s_waitcnt vmcnt(0)" ::: "memory");     // ch=31
  ECMP(1)
#undef ESTG
#undef ECMP

  // ---- epilogue: h-reduce via LDS (alias onto drained staging) ----
  __syncthreads();                  // all waves done reading staging
  float (*Els)[16][64] = (float (*)[16][64])smem;   // 8 KB alias
  *(floatx4*)&Els[h][lo][(q << 4) + (hi << 2)] = acc;
  __syncthreads();

  if (tid < 256){
    int c = tid >> 4, j = tid & 15;
    float4 t0 = *(const float4*)&Els[0][c][4 * j];
    float4 t1 = *(const float4*)&Els[1][c][4 * j];
    float4 e;
    e.x = t0.x + t1.x; e.y = t0.y + t1.y;
    e.z = t0.z + t1.z; e.w = t0.w + t1.w;
    *(float4*)(partial + (((size_t)(half * N_ + n)) * C_ + c0 + c) * K_ + 4 * j) = e;
  }
}

// K2: out = x + scale * softmax(-E) @ y.  Grid 2048 (~8 blocks/CU), 256 thr.
// Prologue: PVLOAD(0) PREFETCHED, then reduce the 2 partial halves (L2-hot),
// softmax(-E), att -> XOR-swizzled attl.  Main loop: swapped MFMA, A straight
// from ytr; T[16][68] transpose -> 256B-contiguous x-load / out-store.
__global__ __launch_bounds__(256) void k_pv(const float* __restrict__ x,
                                            const float* __restrict__ partial,
                                            const unsigned short* __restrict__ ytr,
                                            const float* __restrict__ scale,
                                            float* __restrict__ out){
  __shared__ float T[4][16][68];
  __shared__ char attl[2048];
  int bid = ((blockIdx.x & 7) << 8) | (blockIdx.x >> 3);  // XCD swizzle (2048%8==0)
  int sb = bid & 7;
  int ct = (bid >> 3) & 31;
  int n  = bid >> 8;
  int tid = threadIdx.x;
  int w  = tid >> 6;
  int l  = tid & 63, lo = l & 15, hi = l >> 4;
  int c0 = ct << 4;
  int sP = (sb << 9) + (w << 7);     // 512 per block, 128 per wave
  float sc = scale[0];

  const unsigned short* ybn = ytr + (size_t)n * HW_ * K_;
  float (*Tw)[68] = T[w];
  size_t xb[4];
#pragma unroll
  for (int rg = 0; rg < 4; ++rg)
    xb[rg] = ((size_t)n * C_ + c0 + (rg << 2) + hi) * HW_ + sP + (lo << 2);

  short8 aA[8]; float4 xA[4];
  short8 aB[8]; float4 xB[4];

#define PVLOAD(G, AV, XV)                                                      \
  {                                                                            \
    int sg = sP + (G) * 64;                                                    \
    _Pragma("unroll")                                                          \
    for (int t = 0; t < 4; ++t){                                               \
      const unsigned short* ap = ybn + (size_t)(sg + t * 16 + lo) * K_ + (hi << 3); \
      AV[2 * t]     = *(const short8*)(ap);                                    \
      AV[2 * t + 1] = *(const short8*)(ap + 32);                               \
    }                                                                          \
    _Pragma("unroll")                                                          \
    for (int rg = 0; rg < 4; ++rg)                                             \
      XV[rg] = *(const float4*)(x + xb[rg] + (G) * 64);                        \
  }

#define PVCOMP(G, AV, XV)                                                      \
  {                                                                            \
    _Pragma("unroll")                                                          \
    for (int t = 0; t < 4; ++t){                                               \
      floatx4 a2 = {0.f, 0.f, 0.f, 0.f};                                       \
      a2 = __builtin_amdgcn_mfma_f32_16x16x32_bf16(AV[2 * t],     batt0, a2, 0, 0, 0); \
      a2 = __builtin_amdgcn_mfma_f32_16x16x32_bf16(AV[2 * t + 1], batt1, a2, 0, 0, 0); \
      *(floatx4*)&Tw[lo][t * 16 + (hi << 2)] = a2;   /* D: col=lo->c, row->s */ \
    }                                                                          \
    _Pragma("unroll")                                                          \
    for (int rg = 0; rg < 4; ++rg){                                            \
      float4 v  = *(const float4*)&Tw[(rg << 2) + hi][lo << 2];                \
      float4 xv = XV[rg];                                                      \
      float4 o;                                                                \
      o.x = xv.x + sc * v.x; o.y = xv.y + sc * v.y;                            \
      o.z = xv.z + sc * v.z; o.w = xv.w + sc * v.w;                            \
      *(float4*)(out + xb[rg] + (G) * 64) = o;                                 \
    }                                                                          \
  }

  PVLOAD(0, aA, xA)                 // prefetch: latency hides under softmax

  // ---- softmax prologue ----
  {
    int c = tid >> 4, j = tid & 15;
    const float* pp = partial + ((size_t)n * C_ + c0 + c) * K_ + 4 * j;
    float4 t0 = *(const float4*)(pp);
    float4 t1 = *(const float4*)(pp + (size_t)N_ * C_ * K_);
    float e0 = t0.x + t1.x, e1 = t0.y + t1.y, e2 = t0.z + t1.z, e3 = t0.w + t1.w;
    float m = fminf(fminf(e0, e1), fminf(e2, e3));
#pragma unroll
    for (int off = 8; off; off >>= 1) m = fminf(m, __shfl_xor(m, off, 16));
    float p0 = __expf(m - e0), p1 = __expf(m - e1);
    float p2 = __expf(m - e2), p3 = __expf(m - e3);
    float s = p0 + p1 + p2 + p3;
#pragma unroll
    for (int off = 8; off; off >>= 1) s += __shfl_xor(s, off, 16);
    float inv = 1.f / s;
    unsigned d0, d1;
    asm("v_cvt_pk_bf16_f32 %0, %1, %2" : "=v"(d0) : "v"(p0 * inv), "v"(p1 * inv));
    asm("v_cvt_pk_bf16_f32 %0, %1, %2" : "=v"(d1) : "v"(p2 * inv), "v"(p3 * inv));
    uint2 dd; dd.x = d0; dd.y = d1;
    *(uint2*)(attl + c * 128 + ((8 * j) ^ ((c & 7) << 4))) = dd;
  }
  __syncthreads();

  short8 batt0 = *(const short8*)(attl + lo * 128 + ((     hi * 16) ^ ((lo & 7) << 4)));
  short8 batt1 = *(const short8*)(attl + lo * 128 + ((64 + hi * 16) ^ ((lo & 7) << 4)));

  PVLOAD(1, aB, xB)
  PVCOMP(0, aA, xA)
  PVCOMP(1, aB, xB)
#undef PVLOAD
#undef PVCOMP
}

extern "C" void kernel_launch(void* const* d_in, const int* in_sizes, int n_in,
                              void* d_out, int out_size, void* d_ws, size_t ws_size,
                              hipStream_t stream){
  const float* x     = (const float*)d_in[0];
  const float* y     = (const float*)d_in[1];
  const float* scale = (const float*)d_in[2];
  float* out = (float*)d_out;

  // ws layout (10 MiB):
  //   partial : 2 * N*C*K f32 = 2 MiB @ 0    ([half][n][c][k])
  //   ybf     : N*K*HW bf16   = 4 MiB @ 2 MiB
  //   ytr     : N*HW*K bf16   = 4 MiB @ 6 MiB
  char* ws = (char*)d_ws;
  float*          partial = (float*)(ws);
  unsigned short* ybf     = (unsigned short*)(ws + (2u<<20));
  unsigned short* ytr     = (unsigned short*)(ws + (6u<<20));

  k_prep <<<N_ * (HW_/64), 256, 0, stream>>>(y, ybf, ytr);
  k_esm  <<<N_ * 32 * 2,   512, 0, stream>>>(x, ybf, partial);
  k_pv   <<<N_ * 32 * 8,   256, 0, stream>>>(x, partial, ytr, scale, out);
}